// Round 5
// baseline (391.950 us; speedup 1.0000x reference)
//
#include <hip/hip_runtime.h>
#include <hip/hip_bf16.h>

#define NNODE 1024
#define NGRAPH 4
#define EDIM 768
#define NH 12
#define HD 64
#define NBH 48          // NGRAPH*NH
#define MTOK 4096       // NNODE*NGRAPH
#define QKVN 2304       // 3*EDIM

typedef __attribute__((ext_vector_type(8))) short bf16x8;
typedef __attribute__((ext_vector_type(4))) float f32x4;

// float -> bf16 bits, round-to-nearest-even
static __device__ __forceinline__ short f2s(float f) {
    union { float f; unsigned u; } c; c.f = f;
    unsigned r = (c.u + 0x7FFFu + ((c.u >> 16) & 1u)) >> 16;
    return (short)r;
}

// async global -> LDS, 16B per lane. LDS dest = wave-uniform base + lane*16.
static __device__ __forceinline__ void gload_lds16(const short* g, short* l) {
    __builtin_amdgcn_global_load_lds(
        (const __attribute__((address_space(1))) unsigned int*)g,
        (__attribute__((address_space(3))) unsigned int*)l,
        16, 0, 0);
}

// fp32 -> bf16 elementwise, n divisible by 2048 (grid = n/2048, block 256)
__global__ __launch_bounds__(256) void cvt_bf16(
    const float* __restrict__ in, short* __restrict__ out, int n)
{
    const int i = (blockIdx.x * 256 + threadIdx.x) * 8;
    float4 a = *(const float4*)(in + i);
    float4 b = *(const float4*)(in + i + 4);
    bf16x8 v;
    v[0] = f2s(a.x); v[1] = f2s(a.y); v[2] = f2s(a.z); v[3] = f2s(a.w);
    v[4] = f2s(b.x); v[5] = f2s(b.y); v[6] = f2s(b.z); v[7] = f2s(b.w);
    *(bf16x8*)(out + i) = v;
}

// C[M,N] = A[M,K] @ B[N,K]^T + bias[N].  A,B bf16 bits (global), bias fp32.
// m97-style: 128x128 tile, BK=64, global_load_lds width-16, unpadded LDS.
// mode 0: scale cols < EDIM by 0.125, C bf16 (short*)
// mode 1: zero rows whose (b,n) mask is 0 (row = n*NGRAPH + b), C fp32
__global__ __launch_bounds__(256) void gemm_bt(
    const short* __restrict__ A,
    const short* __restrict__ B,
    const float* __restrict__ bias,
    void* __restrict__ Cv,
    int M, int N, int K, int mode, const int* __restrict__ mask)
{
    __shared__ __align__(16) short As[128 * 64];   // [row][k], unpadded (load_lds)
    __shared__ __align__(16) short Bs[128 * 64];

    const int m0 = blockIdx.x * 128;
    const int n0 = blockIdx.y * 128;
    const int t = threadIdx.x;
    const int w = t >> 6, l = t & 63;
    const int wm = (w & 1) * 64, wn = (w >> 1) * 64;
    const int c = l & 15, g = l >> 4;

    // staging: inst j of wave w covers rows (w*4+j)*8 + (l>>3), col (l&7)*8
    const int srow = l >> 3;
    const int scol = (l & 7) * 8;

    f32x4 acc[4][4];
    #pragma unroll
    for (int i = 0; i < 4; i++)
        #pragma unroll
        for (int j = 0; j < 4; j++)
            acc[i][j] = (f32x4){0.f, 0.f, 0.f, 0.f};

    for (int kt = 0; kt < K; kt += 64) {
        __syncthreads();   // prior tile's ds_reads done before overwrite
        #pragma unroll
        for (int j = 0; j < 4; j++) {
            const int rr = (w * 4 + j) * 8 + srow;
            gload_lds16(A + (size_t)(m0 + rr) * K + kt + scol, &As[(w * 4 + j) * 512]);
            gload_lds16(B + (size_t)(n0 + rr) * K + kt + scol, &Bs[(w * 4 + j) * 512]);
        }
        __syncthreads();   // drains vmcnt (loads landed in LDS)

        #pragma unroll
        for (int ks = 0; ks < 2; ks++) {
            bf16x8 af[4], bf[4];
            #pragma unroll
            for (int i = 0; i < 4; i++)
                af[i] = *(const bf16x8*)&As[(wm + i * 16 + c) * 64 + ks * 32 + g * 8];
            #pragma unroll
            for (int j = 0; j < 4; j++)
                bf[j] = *(const bf16x8*)&Bs[(wn + j * 16 + c) * 64 + ks * 32 + g * 8];
            #pragma unroll
            for (int i = 0; i < 4; i++)
                #pragma unroll
                for (int j = 0; j < 4; j++)
                    acc[i][j] = __builtin_amdgcn_mfma_f32_16x16x32_bf16(af[i], bf[j], acc[i][j], 0, 0, 0);
        }
    }

    // epilogue: C/D layout col = lane&15 (c), row-sub = g*4 + r
    float bcol[4];
    #pragma unroll
    for (int j = 0; j < 4; j++) bcol[j] = bias[n0 + wn + j * 16 + c];

    if (mode == 0) {
        short* Cb = (short*)Cv;
        #pragma unroll
        for (int i = 0; i < 4; i++) {
            #pragma unroll
            for (int r = 0; r < 4; r++) {
                const int row = m0 + wm + i * 16 + g * 4 + r;
                short* crow = Cb + (size_t)row * N + n0 + wn + c;
                #pragma unroll
                for (int j = 0; j < 4; j++) {
                    const int col = n0 + wn + j * 16 + c;
                    float v = acc[i][j][r] + bcol[j];
                    if (col < EDIM) v *= 0.125f;   // q scaling
                    crow[j * 16] = f2s(v);
                }
            }
        }
    } else {
        float* Cf = (float*)Cv;
        float mfac[4][4];
        #pragma unroll
        for (int i = 0; i < 4; i++)
            #pragma unroll
            for (int r = 0; r < 4; r++) {
                const int row = m0 + wm + i * 16 + g * 4 + r;
                mfac[i][r] = mask[(row & 3) * NNODE + (row >> 2)] ? 1.f : 0.f;
            }
        #pragma unroll
        for (int i = 0; i < 4; i++) {
            #pragma unroll
            for (int r = 0; r < 4; r++) {
                const int row = m0 + wm + i * 16 + g * 4 + r;
                float* crow = Cf + (size_t)row * N + n0 + wn + c;
                #pragma unroll
                for (int j = 0; j < 4; j++)
                    crow[j * 16] = (acc[i][j][r] + bcol[j]) * mfac[i][r];
            }
        }
    }
}

// MFMA flash attention: one block = (64 q-rows) x (1 head). 4 waves, each wave
// owns a 16-row q-strip. K-tiles of 64 keys; online softmax in registers;
// bias AND K/V register-prefetched one tile ahead. Output bf16.
#define FLDK 72
#define FLDP 72
__global__ __launch_bounds__(256) void flash_attn(
    const short* __restrict__ qkv,        // [MTOK, QKVN] bf16 bits, q pre-scaled
    const float* __restrict__ attn_bias,  // [NBH, NNODE, NNODE] fp32
    short* __restrict__ attn)             // [MTOK, EDIM] bf16 bits
{
    __shared__ __align__(16) short Ks[64 * FLDK];       // [key][k]
    __shared__ __align__(16) short Vt[64 * FLDK];       // [d][key], xor-swizzled
    __shared__ __align__(16) short Ps[4][16 * FLDP];    // per-wave P strip

    const int bh = blockIdx.y;
    const int b = bh / NH, h = bh - b * NH;
    const int q0 = blockIdx.x * 64;
    const int t = threadIdx.x;
    const int w = t >> 6, l = t & 63;
    const int c = l & 15, g = l >> 4;

    // Q A-fragments (rows w*16+c, k = g*8 + j and +32)
    const int qrow = q0 + w * 16 + c;
    const short* qptr = qkv + (size_t)(qrow * NGRAPH + b) * QKVN + h * HD + g * 8;
    bf16x8 qa0 = *(const bf16x8*)(qptr);
    bf16x8 qa1 = *(const bf16x8*)(qptr + 32);

    // staging indices: thread t covers key-row (t>>3)+32p, 8 k-cols (t&7)*8
    const int skrow = t >> 3;
    const int scol8 = (t & 7) * 8;
    const int sxor = scol8 & 0x38;

    float m_st[4], l_st[4];
    f32x4 o[4];
    #pragma unroll
    for (int r = 0; r < 4; r++) { m_st[r] = -3e38f; l_st[r] = 0.f; }
    #pragma unroll
    for (int ct = 0; ct < 4; ct++) o[ct] = (f32x4){0.f, 0.f, 0.f, 0.f};

    // bias prefetch
    const float* bp_base = attn_bias + (size_t)bh * NNODE * NNODE
                         + (size_t)(q0 + w * 16) * NNODE;
    float bpre[16];
    #pragma unroll
    for (int ct = 0; ct < 4; ct++)
        #pragma unroll
        for (int r = 0; r < 4; r++)
            bpre[ct * 4 + r] = bp_base[(size_t)(g * 4 + r) * NNODE + ct * 16 + c];

    // K/V register prefetch of tile 0
    bf16x8 kk[2], vv[2];
    #pragma unroll
    for (int p = 0; p < 2; p++) {
        const short* kvp = qkv + (size_t)((skrow + p * 32) * NGRAPH + b) * QKVN + h * HD + scol8;
        kk[p] = *(const bf16x8*)(kvp + EDIM);
        vv[p] = *(const bf16x8*)(kvp + 2 * EDIM);
    }

    for (int k0 = 0; k0 < NNODE; k0 += 64) {
        __syncthreads();   // prior tile's LDS reads complete
        #pragma unroll
        for (int p = 0; p < 2; p++) {
            const int kr = skrow + p * 32;
            *(bf16x8*)&Ks[kr * FLDK + scol8] = kk[p];
            const int kks = kr ^ sxor;
            #pragma unroll
            for (int j = 0; j < 8; j++)
                Vt[(scol8 + j) * FLDK + kks] = vv[p][j];
        }
        __syncthreads();

        // prefetch next tile's K/V into regs (wraps to 0 on last tile)
        const int kn = (k0 + 64) & (NNODE - 1);
        #pragma unroll
        for (int p = 0; p < 2; p++) {
            const short* kvp = qkv + (size_t)((kn + skrow + p * 32) * NGRAPH + b) * QKVN + h * HD + scol8;
            kk[p] = *(const bf16x8*)(kvp + EDIM);
            vv[p] = *(const bf16x8*)(kvp + 2 * EDIM);
        }

        // S = bias + Q K^T (C-layout), consume prefetched bias, refill for next
        f32x4 s[4];
        #pragma unroll
        for (int ct = 0; ct < 4; ct++)
            #pragma unroll
            for (int r = 0; r < 4; r++)
                s[ct][r] = bpre[ct * 4 + r];

        const int knext = (k0 + 64) & (NNODE - 1);
        #pragma unroll
        for (int ct = 0; ct < 4; ct++)
            #pragma unroll
            for (int r = 0; r < 4; r++)
                bpre[ct * 4 + r] = bp_base[(size_t)(g * 4 + r) * NNODE + knext + ct * 16 + c];

        #pragma unroll
        for (int ct = 0; ct < 4; ct++) {
            bf16x8 kb0 = *(const bf16x8*)&Ks[(ct * 16 + c) * FLDK + g * 8];
            bf16x8 kb1 = *(const bf16x8*)&Ks[(ct * 16 + c) * FLDK + 32 + g * 8];
            s[ct] = __builtin_amdgcn_mfma_f32_16x16x32_bf16(qa0, kb0, s[ct], 0, 0, 0);
            s[ct] = __builtin_amdgcn_mfma_f32_16x16x32_bf16(qa1, kb1, s[ct], 0, 0, 0);
        }

        // online softmax (row g*4+r lives in 16 lanes of group g)
        float mn[4], alpha[4];
        #pragma unroll
        for (int r = 0; r < 4; r++) {
            float mx = fmaxf(fmaxf(s[0][r], s[1][r]), fmaxf(s[2][r], s[3][r]));
            #pragma unroll
            for (int off = 1; off < 16; off <<= 1)
                mx = fmaxf(mx, __shfl_xor(mx, off));
            mn[r] = fmaxf(m_st[r], mx);
            alpha[r] = __expf(m_st[r] - mn[r]);
            m_st[r] = mn[r];
        }
        float rs[4] = {0.f, 0.f, 0.f, 0.f};
        #pragma unroll
        for (int ct = 0; ct < 4; ct++) {
            #pragma unroll
            for (int r = 0; r < 4; r++) {
                float pv = __expf(s[ct][r] - mn[r]);
                s[ct][r] = pv;
                rs[r] += pv;
            }
        }
        #pragma unroll
        for (int r = 0; r < 4; r++) {
            #pragma unroll
            for (int off = 1; off < 16; off <<= 1)
                rs[r] += __shfl_xor(rs[r], off);
            l_st[r] = alpha[r] * l_st[r] + rs[r];
        }
        #pragma unroll
        for (int ct = 0; ct < 4; ct++)
            #pragma unroll
            for (int r = 0; r < 4; r++)
                o[ct][r] *= alpha[r];

        // P (C-layout) -> LDS -> A-layout; per-wave private (in-order DS pipe)
        short* ps = &Ps[w][0];
        #pragma unroll
        for (int ct = 0; ct < 4; ct++)
            #pragma unroll
            for (int r = 0; r < 4; r++)
                ps[(g * 4 + r) * FLDP + ct * 16 + c] = f2s(s[ct][r]);

        bf16x8 pa0 = *(const bf16x8*)&ps[c * FLDP + g * 8];
        bf16x8 pa1 = *(const bf16x8*)&ps[c * FLDP + 32 + g * 8];
        #pragma unroll
        for (int ct = 0; ct < 4; ct++) {
            const int d = ct * 16 + c;
            const int x = d & 0x38;
            bf16x8 vb0 = *(const bf16x8*)&Vt[d * FLDK + ((g * 8) ^ x)];
            bf16x8 vb1 = *(const bf16x8*)&Vt[d * FLDK + ((32 + g * 8) ^ x)];
            o[ct] = __builtin_amdgcn_mfma_f32_16x16x32_bf16(pa0, vb0, o[ct], 0, 0, 0);
            o[ct] = __builtin_amdgcn_mfma_f32_16x16x32_bf16(pa1, vb1, o[ct], 0, 0, 0);
        }
    }

    float inv[4];
    #pragma unroll
    for (int r = 0; r < 4; r++) inv[r] = 1.f / l_st[r];
    #pragma unroll
    for (int ct = 0; ct < 4; ct++) {
        #pragma unroll
        for (int r = 0; r < 4; r++) {
            const int n = q0 + w * 16 + g * 4 + r;
            attn[(size_t)(n * NGRAPH + b) * EDIM + h * HD + ct * 16 + c] =
                f2s(o[ct][r] * inv[r]);
        }
    }
}

extern "C" void kernel_launch(void* const* d_in, const int* in_sizes, int n_in,
                              void* d_out, int out_size, void* d_ws, size_t ws_size,
                              hipStream_t stream) {
    const float* query     = (const float*)d_in[0];
    const float* attn_bias = (const float*)d_in[1];
    const int*   mask      = (const int*)d_in[2];
    const float* W_in      = (const float*)d_in[3];
    const float* b_in      = (const float*)d_in[4];
    const float* W_out     = (const float*)d_in[5];
    const float* b_out     = (const float*)d_in[6];
    float* out = (float*)d_out;

    // workspace layout (shorts): qkv | attn | q_bf | win_bf | wout_bf
    short* qkv     = (short*)d_ws;                       // [MTOK, QKVN]
    short* attn    = qkv + (size_t)MTOK * QKVN;          // [MTOK, EDIM]
    short* q_bf    = attn + (size_t)MTOK * EDIM;         // [MTOK, EDIM]
    short* win_bf  = q_bf + (size_t)MTOK * EDIM;         // [QKVN, EDIM]
    short* wout_bf = win_bf + (size_t)QKVN * EDIM;       // [EDIM, EDIM]

    // 0) convert fp32 -> bf16
    cvt_bf16<<<(MTOK * EDIM) / 2048, 256, 0, stream>>>(query, q_bf, MTOK * EDIM);
    cvt_bf16<<<(QKVN * EDIM) / 2048, 256, 0, stream>>>(W_in, win_bf, QKVN * EDIM);
    cvt_bf16<<<(EDIM * EDIM) / 2048, 256, 0, stream>>>(W_out, wout_bf, EDIM * EDIM);

    // 1) qkv = q_bf @ W_in^T + b_in  (q part scaled by 0.125), bf16 out
    {
        dim3 grid(MTOK / 128, QKVN / 128);
        gemm_bt<<<grid, 256, 0, stream>>>(q_bf, win_bf, b_in, qkv,
                                          MTOK, QKVN, EDIM, 0, nullptr);
    }
    // 2) MFMA flash attention (bf16 out)
    {
        dim3 grid(NNODE / 64, NBH);
        flash_attn<<<grid, 256, 0, stream>>>(qkv, attn_bias, attn);
    }
    // 3) out = attn @ W_out^T + b_out, masked, fp32 out
    {
        dim3 grid(MTOK / 128, EDIM / 128);
        gemm_bt<<<grid, 256, 0, stream>>>(attn, wout_bf, b_out, out,
                                          MTOK, EDIM, EDIM, 1, mask);
    }
}

// Round 6
// 372.890 us; speedup vs baseline: 1.0511x; 1.0511x over previous
//
#include <hip/hip_runtime.h>
#include <hip/hip_bf16.h>

#define NNODE 1024
#define NGRAPH 4
#define EDIM 768
#define NH 12
#define HD 64
#define NBH 48          // NGRAPH*NH
#define MTOK 4096       // NNODE*NGRAPH
#define QKVN 2304       // 3*EDIM

typedef __attribute__((ext_vector_type(8))) short bf16x8;
typedef __attribute__((ext_vector_type(4))) float f32x4;

// float -> bf16 bits, round-to-nearest-even
static __device__ __forceinline__ short f2s(float f) {
    union { float f; unsigned u; } c; c.f = f;
    unsigned r = (c.u + 0x7FFFu + ((c.u >> 16) & 1u)) >> 16;
    return (short)r;
}

// async global -> LDS, 16B per lane. LDS dest = wave-uniform base + lane*16.
static __device__ __forceinline__ void gload_lds16(const short* g, short* l) {
    __builtin_amdgcn_global_load_lds(
        (const __attribute__((address_space(1))) unsigned int*)g,
        (__attribute__((address_space(3))) unsigned int*)l,
        16, 0, 0);
}

// fused fp32 -> bf16 for 3 tensors; each block converts 2048 elems
__global__ __launch_bounds__(256) void cvt3_bf16(
    const float* __restrict__ a, short* __restrict__ oa, int ba,
    const float* __restrict__ b, short* __restrict__ ob, int bb,
    const float* __restrict__ c2, short* __restrict__ oc)
{
    int bid = blockIdx.x;
    const float* in; short* out;
    if (bid < ba) { in = a; out = oa; }
    else if (bid < ba + bb) { bid -= ba; in = b; out = ob; }
    else { bid -= ba + bb; in = c2; out = oc; }
    const int i = (bid * 256 + threadIdx.x) * 8;
    float4 x = *(const float4*)(in + i);
    float4 y = *(const float4*)(in + i + 4);
    bf16x8 v;
    v[0] = f2s(x.x); v[1] = f2s(x.y); v[2] = f2s(x.z); v[3] = f2s(x.w);
    v[4] = f2s(y.x); v[5] = f2s(y.y); v[6] = f2s(y.z); v[7] = f2s(y.w);
    *(bf16x8*)(out + i) = v;
}

// C[M,N] = A[M,K] @ B[N,K]^T + bias[N].  A,B bf16 bits (global), bias fp32.
// m97-style: 128x128 tile, BK=64, global_load_lds width-16, unpadded LDS.
// mode 0: scale cols < EDIM by 0.125, C bf16 (short*)
// mode 1: zero rows whose (b,n) mask is 0 (row = n*NGRAPH + b), C fp32
__global__ __launch_bounds__(256) void gemm_bt(
    const short* __restrict__ A,
    const short* __restrict__ B,
    const float* __restrict__ bias,
    void* __restrict__ Cv,
    int M, int N, int K, int mode, const int* __restrict__ mask)
{
    __shared__ __align__(16) short As[128 * 64];   // [row][k], unpadded (load_lds)
    __shared__ __align__(16) short Bs[128 * 64];

    const int m0 = blockIdx.x * 128;
    const int n0 = blockIdx.y * 128;
    const int t = threadIdx.x;
    const int w = t >> 6, l = t & 63;
    const int wm = (w & 1) * 64, wn = (w >> 1) * 64;
    const int c = l & 15, g = l >> 4;

    const int srow = l >> 3;
    const int scol = (l & 7) * 8;

    f32x4 acc[4][4];
    #pragma unroll
    for (int i = 0; i < 4; i++)
        #pragma unroll
        for (int j = 0; j < 4; j++)
            acc[i][j] = (f32x4){0.f, 0.f, 0.f, 0.f};

    for (int kt = 0; kt < K; kt += 64) {
        __syncthreads();
        #pragma unroll
        for (int j = 0; j < 4; j++) {
            const int rr = (w * 4 + j) * 8 + srow;
            gload_lds16(A + (size_t)(m0 + rr) * K + kt + scol, &As[(w * 4 + j) * 512]);
            gload_lds16(B + (size_t)(n0 + rr) * K + kt + scol, &Bs[(w * 4 + j) * 512]);
        }
        __syncthreads();

        #pragma unroll
        for (int ks = 0; ks < 2; ks++) {
            bf16x8 af[4], bf[4];
            #pragma unroll
            for (int i = 0; i < 4; i++)
                af[i] = *(const bf16x8*)&As[(wm + i * 16 + c) * 64 + ks * 32 + g * 8];
            #pragma unroll
            for (int j = 0; j < 4; j++)
                bf[j] = *(const bf16x8*)&Bs[(wn + j * 16 + c) * 64 + ks * 32 + g * 8];
            #pragma unroll
            for (int i = 0; i < 4; i++)
                #pragma unroll
                for (int j = 0; j < 4; j++)
                    acc[i][j] = __builtin_amdgcn_mfma_f32_16x16x32_bf16(af[i], bf[j], acc[i][j], 0, 0, 0);
        }
    }

    // epilogue: C/D layout col = lane&15 (c), row-sub = g*4 + r
    float bcol[4];
    #pragma unroll
    for (int j = 0; j < 4; j++) bcol[j] = bias[n0 + wn + j * 16 + c];

    if (mode == 0) {
        short* Cb = (short*)Cv;
        #pragma unroll
        for (int i = 0; i < 4; i++) {
            #pragma unroll
            for (int r = 0; r < 4; r++) {
                const int row = m0 + wm + i * 16 + g * 4 + r;
                short* crow = Cb + (size_t)row * N + n0 + wn + c;
                #pragma unroll
                for (int j = 0; j < 4; j++) {
                    const int col = n0 + wn + j * 16 + c;
                    float v = acc[i][j][r] + bcol[j];
                    if (col < EDIM) v *= 0.125f;   // q scaling
                    crow[j * 16] = f2s(v);
                }
            }
        }
    } else {
        float* Cf = (float*)Cv;
        float mfac[4][4];
        #pragma unroll
        for (int i = 0; i < 4; i++)
            #pragma unroll
            for (int r = 0; r < 4; r++) {
                const int row = m0 + wm + i * 16 + g * 4 + r;
                mfac[i][r] = mask[(row & 3) * NNODE + (row >> 2)] ? 1.f : 0.f;
            }
        #pragma unroll
        for (int i = 0; i < 4; i++) {
            #pragma unroll
            for (int r = 0; r < 4; r++) {
                const int row = m0 + wm + i * 16 + g * 4 + r;
                float* crow = Cf + (size_t)row * N + n0 + wn + c;
                #pragma unroll
                for (int j = 0; j < 4; j++)
                    crow[j * 16] = (acc[i][j][r] + bcol[j]) * mfac[i][r];
            }
        }
    }
}

// MFMA flash attention (round-4 body): one block = 64 q-rows x 1 head, 4 waves.
// K-tiles of 64 keys; online softmax in registers; bias prefetched one tile
// ahead with nontemporal loads. Output bf16.
#define FLDK 72
#define FLDP 72
__global__ __launch_bounds__(256) void flash_attn(
    const short* __restrict__ qkv,        // [MTOK, QKVN] bf16 bits, q pre-scaled
    const float* __restrict__ attn_bias,  // [NBH, NNODE, NNODE] fp32
    short* __restrict__ attn)             // [MTOK, EDIM] bf16 bits
{
    __shared__ __align__(16) short Ks[64 * FLDK];       // [key][k]
    __shared__ __align__(16) short Vt[64 * FLDK];       // [d][key], xor-swizzled
    __shared__ __align__(16) short Ps[4][16 * FLDP];    // per-wave P strip

    const int bh = blockIdx.y;
    const int b = bh / NH, h = bh - b * NH;
    const int q0 = blockIdx.x * 64;
    const int t = threadIdx.x;
    const int w = t >> 6, l = t & 63;
    const int c = l & 15, g = l >> 4;

    // Q A-fragments (rows w*16+c, k = g*8 + j and +32)
    const int qrow = q0 + w * 16 + c;
    const short* qptr = qkv + (size_t)(qrow * NGRAPH + b) * QKVN + h * HD + g * 8;
    bf16x8 qa0 = *(const bf16x8*)(qptr);
    bf16x8 qa1 = *(const bf16x8*)(qptr + 32);

    // staging indices: thread t covers key-row (t>>3)+32p, 8 k-cols (t&7)*8
    const int skrow = t >> 3;
    const int scol8 = (t & 7) * 8;
    const int sxor = scol8 & 0x38;

    float m_st[4], l_st[4];
    f32x4 o[4];
    #pragma unroll
    for (int r = 0; r < 4; r++) { m_st[r] = -3e38f; l_st[r] = 0.f; }
    #pragma unroll
    for (int ct = 0; ct < 4; ct++) o[ct] = (f32x4){0.f, 0.f, 0.f, 0.f};

    // bias prefetch (nontemporal: read-once stream, keep out of L2)
    const float* bp_base = attn_bias + (size_t)bh * NNODE * NNODE
                         + (size_t)(q0 + w * 16) * NNODE;
    float bpre[16];
    #pragma unroll
    for (int ct = 0; ct < 4; ct++)
        #pragma unroll
        for (int r = 0; r < 4; r++)
            bpre[ct * 4 + r] = __builtin_nontemporal_load(
                bp_base + (size_t)(g * 4 + r) * NNODE + ct * 16 + c);

    for (int k0 = 0; k0 < NNODE; k0 += 64) {
        __syncthreads();   // prior tile's LDS reads complete
        #pragma unroll
        for (int p = 0; p < 2; p++) {
            const int kr = skrow + p * 32;
            const short* kvp = qkv + (size_t)((k0 + kr) * NGRAPH + b) * QKVN + h * HD + scol8;
            bf16x8 kk = *(const bf16x8*)(kvp + EDIM);
            bf16x8 vv = *(const bf16x8*)(kvp + 2 * EDIM);
            *(bf16x8*)&Ks[kr * FLDK + scol8] = kk;
            const int kks = kr ^ sxor;
            #pragma unroll
            for (int j = 0; j < 8; j++)
                Vt[(scol8 + j) * FLDK + kks] = vv[j];
        }
        __syncthreads();

        // S = bias + Q K^T (C-layout); consume prefetched bias, refill for next
        f32x4 s[4];
        #pragma unroll
        for (int ct = 0; ct < 4; ct++)
            #pragma unroll
            for (int r = 0; r < 4; r++)
                s[ct][r] = bpre[ct * 4 + r];

        const int knext = (k0 + 64) & (NNODE - 1);
        #pragma unroll
        for (int ct = 0; ct < 4; ct++)
            #pragma unroll
            for (int r = 0; r < 4; r++)
                bpre[ct * 4 + r] = __builtin_nontemporal_load(
                    bp_base + (size_t)(g * 4 + r) * NNODE + knext + ct * 16 + c);

        #pragma unroll
        for (int ct = 0; ct < 4; ct++) {
            bf16x8 kb0 = *(const bf16x8*)&Ks[(ct * 16 + c) * FLDK + g * 8];
            bf16x8 kb1 = *(const bf16x8*)&Ks[(ct * 16 + c) * FLDK + 32 + g * 8];
            s[ct] = __builtin_amdgcn_mfma_f32_16x16x32_bf16(qa0, kb0, s[ct], 0, 0, 0);
            s[ct] = __builtin_amdgcn_mfma_f32_16x16x32_bf16(qa1, kb1, s[ct], 0, 0, 0);
        }

        // online softmax (row g*4+r lives in 16 lanes of group g)
        float mn[4], alpha[4];
        #pragma unroll
        for (int r = 0; r < 4; r++) {
            float mx = fmaxf(fmaxf(s[0][r], s[1][r]), fmaxf(s[2][r], s[3][r]));
            #pragma unroll
            for (int off = 1; off < 16; off <<= 1)
                mx = fmaxf(mx, __shfl_xor(mx, off));
            mn[r] = fmaxf(m_st[r], mx);
            alpha[r] = __expf(m_st[r] - mn[r]);
            m_st[r] = mn[r];
        }
        float rs[4] = {0.f, 0.f, 0.f, 0.f};
        #pragma unroll
        for (int ct = 0; ct < 4; ct++) {
            #pragma unroll
            for (int r = 0; r < 4; r++) {
                float pv = __expf(s[ct][r] - mn[r]);
                s[ct][r] = pv;
                rs[r] += pv;
            }
        }
        #pragma unroll
        for (int r = 0; r < 4; r++) {
            #pragma unroll
            for (int off = 1; off < 16; off <<= 1)
                rs[r] += __shfl_xor(rs[r], off);
            l_st[r] = alpha[r] * l_st[r] + rs[r];
        }
        #pragma unroll
        for (int ct = 0; ct < 4; ct++)
            #pragma unroll
            for (int r = 0; r < 4; r++)
                o[ct][r] *= alpha[r];

        // P (C-layout) -> LDS -> A-layout; per-wave private (in-order DS pipe)
        short* ps = &Ps[w][0];
        #pragma unroll
        for (int ct = 0; ct < 4; ct++)
            #pragma unroll
            for (int r = 0; r < 4; r++)
                ps[(g * 4 + r) * FLDP + ct * 16 + c] = f2s(s[ct][r]);

        bf16x8 pa0 = *(const bf16x8*)&ps[c * FLDP + g * 8];
        bf16x8 pa1 = *(const bf16x8*)&ps[c * FLDP + 32 + g * 8];
        #pragma unroll
        for (int ct = 0; ct < 4; ct++) {
            const int d = ct * 16 + c;
            const int x = d & 0x38;
            bf16x8 vb0 = *(const bf16x8*)&Vt[d * FLDK + ((g * 8) ^ x)];
            bf16x8 vb1 = *(const bf16x8*)&Vt[d * FLDK + ((32 + g * 8) ^ x)];
            o[ct] = __builtin_amdgcn_mfma_f32_16x16x32_bf16(pa0, vb0, o[ct], 0, 0, 0);
            o[ct] = __builtin_amdgcn_mfma_f32_16x16x32_bf16(pa1, vb1, o[ct], 0, 0, 0);
        }
    }

    float inv[4];
    #pragma unroll
    for (int r = 0; r < 4; r++) inv[r] = 1.f / l_st[r];
    #pragma unroll
    for (int ct = 0; ct < 4; ct++) {
        #pragma unroll
        for (int r = 0; r < 4; r++) {
            const int n = q0 + w * 16 + g * 4 + r;
            attn[(size_t)(n * NGRAPH + b) * EDIM + h * HD + ct * 16 + c] =
                f2s(o[ct][r] * inv[r]);
        }
    }
}

extern "C" void kernel_launch(void* const* d_in, const int* in_sizes, int n_in,
                              void* d_out, int out_size, void* d_ws, size_t ws_size,
                              hipStream_t stream) {
    const float* query     = (const float*)d_in[0];
    const float* attn_bias = (const float*)d_in[1];
    const int*   mask      = (const int*)d_in[2];
    const float* W_in      = (const float*)d_in[3];
    const float* b_in      = (const float*)d_in[4];
    const float* W_out     = (const float*)d_in[5];
    const float* b_out     = (const float*)d_in[6];
    float* out = (float*)d_out;

    // workspace layout (shorts): qkv | attn | q_bf | win_bf | wout_bf
    short* qkv     = (short*)d_ws;                       // [MTOK, QKVN]
    short* attn    = qkv + (size_t)MTOK * QKVN;          // [MTOK, EDIM]
    short* q_bf    = attn + (size_t)MTOK * EDIM;         // [MTOK, EDIM]
    short* win_bf  = q_bf + (size_t)MTOK * EDIM;         // [QKVN, EDIM]
    short* wout_bf = win_bf + (size_t)QKVN * EDIM;       // [EDIM, EDIM]

    // 0) fused fp32 -> bf16 conversion (query, W_in, W_out)
    {
        const int ba = (MTOK * EDIM) / 2048;   // 1536
        const int bb = (QKVN * EDIM) / 2048;   // 864
        const int bc = (EDIM * EDIM) / 2048;   // 288
        cvt3_bf16<<<ba + bb + bc, 256, 0, stream>>>(query, q_bf, ba,
                                                    W_in, win_bf, bb,
                                                    W_out, wout_bf);
    }
    // 1) qkv = q_bf @ W_in^T + b_in  (q part scaled by 0.125), bf16 out
    {
        dim3 grid(MTOK / 128, QKVN / 128);
        gemm_bt<<<grid, 256, 0, stream>>>(q_bf, win_bf, b_in, qkv,
                                          MTOK, QKVN, EDIM, 0, nullptr);
    }
    // 2) MFMA flash attention (bf16 out)
    {
        dim3 grid(NNODE / 64, NBH);
        flash_attn<<<grid, 256, 0, stream>>>(qkv, attn_bias, attn);
    }
    // 3) out = attn @ W_out^T + b_out, masked, fp32 out
    {
        dim3 grid(MTOK / 128, EDIM / 128);
        gemm_bt<<<grid, 256, 0, stream>>>(attn, wout_bf, b_out, out,
                                          MTOK, EDIM, EDIM, 1, mask);
    }
}